// Round 11
// baseline (491.652 us; speedup 1.0000x reference)
//
#include <hip/hip_runtime.h>
#include <hip/hip_bf16.h>

#define BATCH 4
#define NPTS  8192
#define DIM   128
#define KNN   16
#define NROWS (BATCH * NPTS)   // 32768

#define SPLITS 16
#define RANGE  512             // candidates per split
#define TILE   256             // candidates per drain granule
#define LWIN   512             // limpass window width
#define NWIN   4               // limpass windows (NWIN*LWIN = 2048 cands per bound)

using u64  = unsigned long long;
using u32  = unsigned int;

__device__ __forceinline__ unsigned short f2bf(float f) {
    u32 u = __float_as_uint(f);
    u32 r = (u + 0x7FFFu + ((u >> 16) & 1u)) >> 16;  // RTNE
    return (unsigned short)r;
}
// monotone float -> uint mapping (handles negatives, e.g. self-distance ~ -1e-7)
__device__ __forceinline__ u32 fordkey(float f) {
    u32 u = __float_as_uint(f);
    return (u & 0x80000000u) ? ~u : (u | 0x80000000u);
}
// exact inverse of fordkey
__device__ __forceinline__ float invkey(u32 k) {
    u32 u = (k & 0x80000000u) ? (k & 0x7FFFFFFFu) : ~k;
    return __uint_as_float(u);
}

// u32 chain: compiles to v_min_u32/v_max_u32 pairs (2 VALU/step, 32 total)
__device__ __forceinline__ void insert16u(u32 key, u32* ks) {
    if (key < ks[15]) {
#pragma unroll
        for (int t = 0; t < 16; ++t) {
            u32 lo = key < ks[t] ? key : ks[t];
            u32 hi = key < ks[t] ? ks[t] : key;
            ks[t] = lo;
            key = hi;
        }
    }
}

// exact numpy fp32 op order: (sq_i + sq_j) - 2*((xx+yy)+zz)   [proven in R2]
__device__ __forceinline__ float pdist(float4 me, float4 c) {
    float dot = __fadd_rn(__fadd_rn(__fmul_rn(me.x, c.x), __fmul_rn(me.y, c.y)),
                          __fmul_rn(me.z, c.z));
    return __fsub_rn(__fadd_rn(me.w, c.w), __fmul_rn(2.0f, dot));
}

// ---------------------------------------------------------------- weights prep
__global__ __launch_bounds__(256) void prep_weights(const float* __restrict__ Wk,
                                                    const float* __restrict__ Wp2,
                                                    float* __restrict__ wk,
                                                    float* __restrict__ w2) {
    int tid = threadIdx.x;
    int c = tid & 127;
    const float* src = (tid < 128) ? Wk : Wp2;
    float s = 0.f;
    for (int d = 0; d < DIM; ++d) s += src[c * DIM + d];
    if (tid < 128) wk[c] = s;
    else           w2[c] = s;
}

// convert Wv / Wp2 / Wo to packed bf16 pairs, once (L2-resident afterwards)
__global__ __launch_bounds__(256) void conv_weights(const float* __restrict__ Wv,
                                                    const float* __restrict__ Wp2,
                                                    const float* __restrict__ Wo,
                                                    u32* __restrict__ Wb) {
    int i = blockIdx.x * 256 + threadIdx.x;   // 0 .. 3*8192-1
    int which = i >> 13, off = i & 8191;
    const float* W = (which == 0) ? Wv : (which == 1 ? Wp2 : Wo);
    float2 w = ((const float2*)W)[off];
    Wb[i] = (u32)f2bf(w.x) | ((u32)f2bf(w.y) << 16);
}

// ---------------------------------------------------------------- points prep
__global__ __launch_bounds__(256) void prep_points(const float* __restrict__ xyz,
                                                   const float* __restrict__ feat,
                                                   const float* __restrict__ wk,
                                                   float4* __restrict__ pts,
                                                   float* __restrict__ sK) {
    int lid = threadIdx.x & 63;
    int p = blockIdx.x * 4 + (threadIdx.x >> 6);
    float f_lo = feat[(size_t)p * DIM + lid];
    float f_hi = feat[(size_t)p * DIM + 64 + lid];
    float s = fmaf(f_lo, wk[lid], f_hi * wk[64 + lid]);
#pragma unroll
    for (int m = 32; m >= 1; m >>= 1) s += __shfl_xor(s, m);
    if (lid == 0) {
        float x = xyz[p * 3 + 0];
        float y = xyz[p * 3 + 1];
        float z = xyz[p * 3 + 2];
        float sq = __fadd_rn(__fadd_rn(__fmul_rn(x, x), __fmul_rn(y, y)), __fmul_rn(z, z));
        pts[p] = make_float4(x, y, z, sq);
        sK[p] = s;
    }
}

// ---------------------------------------------------------------- KNN limpass
// Per query q and window y: 16 kept approx distances over the 512 candidates
// [y*512,(y+1)*512) of q's batch -> dl16q[q*64 + y*16 ..] (UNSORTED).
// Top-16 as FOUR independent sorted-4 chains (8 ops/fire vs 32) -- R9 win.
// R10 lesson applied: candidates are read DIRECTLY from global with a
// wave-uniform address (single L1 broadcast request/load, ~2x LDS-broadcast
// throughput) -- no LDS tile, no staging writes, no barriers. The -0.5f*c.w
// s-form scale moved inline (mul by 0.5 exact) -> all values bit-identical.
__global__ __launch_bounds__(256) void knn_limpass(const float4* __restrict__ pts,
                                                   float* __restrict__ dl16q) {
    int y = blockIdx.y;
    int wavein = threadIdx.x >> 6, lane = threadIdx.x & 63;
    int q = blockIdx.x * 256 + wavein * 64 + lane;
    int b = blockIdx.x >> 5;   // 256 queries/block, 8192/batch -> provably uniform
    float4 me = pts[q];
    const float4* wb = pts + b * NPTS + y * LWIN;   // wave-uniform window base

    float c0[4], c1[4], c2[4], c3[4];
#pragma unroll
    for (int t = 0; t < 4; ++t) { c0[t] = INFINITY; c1[t] = INFINITY;
                                  c2[t] = INFINITY; c3[t] = INFINITY; }
    float lim = INFINITY;
    float A = -INFINITY;

#define INS4(CH, DV)                                                          \
    if ((DV) < CH[3]) {                                                       \
        float dd_ = (DV);                                                     \
        _Pragma("unroll")                                                     \
        for (int t_ = 0; t_ < 4; ++t_) {                                      \
            float lo_ = fminf(dd_, CH[t_]);                                   \
            float hi_ = fmaxf(dd_, CH[t_]);                                   \
            CH[t_] = lo_; dd_ = hi_;                                          \
        }                                                                     \
    }

    // warmup: first 32 candidates direct into chains (jj&3 compile-time)
#pragma unroll
    for (int jj = 0; jj < 32; ++jj) {
        float4 c = wb[jj];
        float cw = -0.5f * c.w;
        float s = fmaf(me.x, c.x, fmaf(me.y, c.y, fmaf(me.z, c.z, cw)));
        float d = fmaf(-2.0f, s, me.w);
        if ((jj & 3) == 0)      { INS4(c0, d); }
        else if ((jj & 3) == 1) { INS4(c1, d); }
        else if ((jj & 3) == 2) { INS4(c2, d); }
        else                    { INS4(c3, d); }
    }
    lim = fmaxf(fmaxf(c0[3], c1[3]), fmaxf(c2[3], c3[3]));
    A = 0.5f * (me.w - lim);

    for (int cw0 = 32; cw0 < LWIN; cw0 += 32) {
        u32 mask = 0;
#pragma unroll
        for (int jj = 0; jj < 32; ++jj) {
            float4 c = wb[cw0 + jj];
            float cw = -0.5f * c.w;
            float s = fmaf(me.x, c.x, fmaf(me.y, c.y, fmaf(me.z, c.z, cw)));
            mask = (mask << 1) | (u32)(s >= A);       // bit (31-jj) <- cand cw0+jj
        }
#define POP_INS(CH)                                                           \
        if (mask) {                                                           \
            int pos_ = __builtin_ctz(mask); mask &= mask - 1;                 \
            int jj_ = cw0 + 31 - pos_;                                        \
            float4 c_ = wb[jj_];                                              \
            float cw_ = -0.5f * c_.w;                                         \
            float s_ = fmaf(me.x, c_.x,                                       \
                        fmaf(me.y, c_.y, fmaf(me.z, c_.z, cw_)));             \
            float d_ = fmaf(-2.0f, s_, me.w);                                 \
            INS4(CH, d_);                                                     \
        }
        while (mask) {
            POP_INS(c0);
            POP_INS(c1);
            POP_INS(c2);
            POP_INS(c3);
        }
#undef POP_INS
        lim = fmaxf(fmaxf(c0[3], c1[3]), fmaxf(c2[3], c3[3]));
        A = 0.5f * (me.w - lim);
    }
#undef INS4
    float4* dst = (float4*)(dl16q + (size_t)q * 64 + y * 16);
    dst[0] = make_float4(c0[0], c0[1], c0[2], c0[3]);
    dst[1] = make_float4(c1[0], c1[1], c1[2], c1[3]);
    dst[2] = make_float4(c2[0], c2[1], c2[2], c2[3]);
    dst[3] = make_float4(c3[0], c3[1], c3[2], c3[3]);
}

// ---------------------------------------------------------------- bound merge
// One wave per query: 64 lanes hold the 4x16 window distances (unsorted);
// 16 rounds of wave-min extraction yield the 16th-of-64-kept (ties only
// inflate the result -> still a valid upper bound on the global 16th-NN).
__global__ __launch_bounds__(256) void bound_merge(const float* __restrict__ dl16q,
                                                   float* __restrict__ Tq) {
    int wavein = threadIdx.x >> 6, lane = threadIdx.x & 63;
    int q = blockIdx.x * 4 + wavein;
    float v = dl16q[(size_t)q * 64 + lane];
    float got = v;
#pragma unroll
    for (int it = 0; it < 16; ++it) {
        float m = v;
#pragma unroll
        for (int s = 32; s >= 1; s >>= 1) m = fminf(m, __shfl_xor(m, s));
        if (v == m) v = INFINITY;   // clear winner(s); ties only over-estimate
        got = m;
    }
    if (lane == 0) Tq[q] = got;
}

// ---------------------------------------------------------------- KNN partial
// grid (128, SPLITS); split r covers [r*512,(r+1)*512). Gate T = 16th-of-kept
// bound (rank ~70) -> survivors ~4-5/lane/split. Bitmask scan with DIRECT
// wave-uniform global reads (R10 lesson: L1 broadcasts a same-address wave64
// load as one request, ~2x LDS-broadcast throughput; no staging, no
// barriers, no LDS). Drain deferred per 256-granule via 8 mask words +
// skip-empty select chain; drains recompute the same fp sequence -> keys
// bit-identical to R9. ONE query per thread (R6/R7: Q-blocking spills).
// Chain keys u32: top-19 bits of fordkey(d~) | 13-bit idx (merge re-ranks
// exactly). Sentinel 0xFFFFFFFF; gate ratchets via quantization-cell upper
// bound + 1e-4 slop. part16 QUERY-MAJOR: part16[q*256 + r*16 + t]; 0xFFFF empty.
__global__ __launch_bounds__(256) void knn_partial(const float4* __restrict__ pts,
                                                   const float* __restrict__ Tq,
                                                   unsigned short* __restrict__ part16) {
    int r = blockIdx.y;
    int wavein = threadIdx.x >> 6, lane = threadIdx.x & 63;
    int q = blockIdx.x * 256 + wavein * 64 + lane;
    int b = blockIdx.x >> 5;   // 256 q/block, 32 blocks/batch -> uniform (== q>>13)
    float4 me = pts[q];
    const float4* sp = pts + b * NPTS + r * RANGE;    // wave-uniform split base

    float gate_d = Tq[q] + 2.0e-4f;                   // admits all true 16-NN
    u32 kk[16];
#pragma unroll
    for (int t = 0; t < 16; ++t) kk[t] = 0xFFFFFFFFu;
    float A = 0.5f * (me.w - gate_d) - 1.0e-4f;       // s >= A <=> d~ <= gate_d (+slop)

    for (int tb = 0; tb < RANGE / TILE; ++tb) {
        int jb = r * RANGE + tb * TILE;
        const float4* tp = sp + tb * TILE;

        u32 m[8];
#pragma unroll
        for (int w = 0; w < 8; ++w) {
            u32 mask = 0;
#pragma unroll
            for (int jj = 0; jj < 32; ++jj) {
                float4 c = tp[w * 32 + jj];
                float cw = -0.5f * c.w;
                float s = fmaf(me.x, c.x, fmaf(me.y, c.y, fmaf(me.z, c.z, cw)));
                mask = (mask << 1) | (u32)(s >= A);   // bit (31-jj) <- cand w*32+jj
            }
            m[w] = mask;
        }
        int cnt = __popc(m[0]) + __popc(m[1]) + __popc(m[2]) + __popc(m[3]) +
                  __popc(m[4]) + __popc(m[5]) + __popc(m[6]) + __popc(m[7]);

        u32 cur = m[0];
        int w = 0;
        for (int i = 0; i < cnt; ++i) {               // exec-masked to wave-max
            while (cur == 0) {                        // skip empty words (<=7 total)
                ++w;
                cur = (w == 1) ? m[1] : (w == 2) ? m[2] : (w == 3) ? m[3] :
                      (w == 4) ? m[4] : (w == 5) ? m[5] : (w == 6) ? m[6] : m[7];
            }
            int pos = __builtin_ctz(cur);
            cur &= cur - 1;
            int jj = (w << 5) + (31 - pos);
            float4 c = tp[jj];
            float cw = -0.5f * c.w;
            float s = fmaf(me.x, c.x, fmaf(me.y, c.y, fmaf(me.z, c.z, cw)));
            float dt = fmaf(-2.0f, s, me.w);           // same fp sequence as scan
            u32 key = (fordkey(dt) & 0xFFFFE000u) | (u32)(jb + jj);
            insert16u(key, kk);
        }
        // ratchet: quantization-cell upper bound of current 16th + slop.
        // sentinel (0xFFFFFFFF) -> invkey = NaN -> comparison false -> no-op.
        float nl = invkey((kk[15] & 0xFFFFE000u) | 0x1FFFu) + 1.0e-4f;
        gate_d = (nl < gate_d) ? nl : gate_d;          // monotone ratchet
        A = 0.5f * (me.w - gate_d) - 1.0e-4f;
    }
    u32* dst = (u32*)(part16 + (size_t)q * 256 + r * 16);
#pragma unroll
    for (int t = 0; t < 8; ++t) {
        u32 a = kk[2 * t], c = kk[2 * t + 1];
        u32 i0 = (a == 0xFFFFFFFFu) ? 0xFFFFu : (a & 0x1FFFu);
        u32 i1 = (c == 0xFFFFFFFFu) ? 0xFFFFu : (c & 0x1FFFu);
        dst[t] = i0 | (i1 << 16);
    }
}

// ---------------------------------------------------------------- KNN merge
// One WAVE per query. Keys are (hi=fordkey(exact d), lo=idx) pairs kept in
// separate u32 regs. Extraction rounds reduce ONLY the hi word (6 x {shfl_xor
// + v_min_u32}); the winner's lo is fetched with one shuffle when the hi-min
// is unique (ballot popcount == 1, the ~always case, wave-uniform branch) or
// via a second masked u32 reduce on a genuine distance tie. Selection order
// is exactly (d, idx)-lexicographic == the serial exact-key merge.
__global__ __launch_bounds__(256) void knn_merge(const float4* __restrict__ pts,
                                                 const unsigned short* __restrict__ part16,
                                                 int* __restrict__ idx16) {
    int wavein = threadIdx.x >> 6, lane = threadIdx.x & 63;
    int q = blockIdx.x * 4 + wavein;
    int b = q >> 13;
    float4 me = pts[q];
    ushort4 e = *(const ushort4*)(part16 + (size_t)q * 256 + lane * 4);
    u64 k0, k1, k2, k3;
    {
        u32 id, ida;
        id = e.x; ida = (id != 0xFFFFu) ? id : 0u;
        k0 = (id != 0xFFFFu) ? (((u64)fordkey(pdist(me, pts[b * NPTS + ida])) << 32) | id) : ~0ull;
        id = e.y; ida = (id != 0xFFFFu) ? id : 0u;
        k1 = (id != 0xFFFFu) ? (((u64)fordkey(pdist(me, pts[b * NPTS + ida])) << 32) | id) : ~0ull;
        id = e.z; ida = (id != 0xFFFFu) ? id : 0u;
        k2 = (id != 0xFFFFu) ? (((u64)fordkey(pdist(me, pts[b * NPTS + ida])) << 32) | id) : ~0ull;
        id = e.w; ida = (id != 0xFFFFu) ? id : 0u;
        k3 = (id != 0xFFFFu) ? (((u64)fordkey(pdist(me, pts[b * NPTS + ida])) << 32) | id) : ~0ull;
    }
    // sort4 (network: (0,1)(2,3)(0,2)(1,3)(1,2)) on full u64 keys (reg-only)
    u64 t;
    if (k1 < k0) { t = k0; k0 = k1; k1 = t; }
    if (k3 < k2) { t = k2; k2 = k3; k3 = t; }
    if (k2 < k0) { t = k0; k0 = k2; k2 = t; }
    if (k3 < k1) { t = k1; k1 = k3; k3 = t; }
    if (k2 < k1) { t = k1; k1 = k2; k2 = t; }

    u32 curh = (u32)(k0 >> 32), curl = (u32)k0;
    int head = 0;
    u32 gotl = 0;
#pragma unroll
    for (int it = 0; it < 16; ++it) {
        u32 mh = curh;
#pragma unroll
        for (int s = 32; s >= 1; s >>= 1) {
            u32 o = __shfl_xor(mh, s);
            mh = (o < mh) ? o : mh;
        }
        u64 bal = __ballot(curh == mh);
        u32 wlo;
        if (__builtin_popcountll(bal) == 1) {         // unique hi-min (~always)
            int wl = __builtin_ctzll(bal);
            wlo = __shfl(curl, wl);
        } else {                                      // exact-distance tie: min idx
            u32 cand = (curh == mh) ? curl : 0xFFFFFFFFu;
#pragma unroll
            for (int s = 32; s >= 1; s >>= 1) {
                u32 o = __shfl_xor(cand, s);
                cand = (o < cand) ? o : cand;
            }
            wlo = cand;
        }
        if (curh == mh && curl == wlo) {              // winner advances its head
            head++;
            u64 nx = (head == 1) ? k1 : (head == 2) ? k2 : (head == 3) ? k3 : ~0ull;
            curh = (u32)(nx >> 32);
            curl = (u32)nx;
        }
        if (lane == it) gotl = wlo;
    }
    if (lane < 16) idx16[q * KNN + lane] = (int)gotl;
}

// ---------------------------------------------------------------- GEMM 32-row
// X fp32, W pre-packed bf16 pairs (global, staged to LDS), accum fp32.
// MODE 0: Vf   = X @ Wv + bv                      -> fp32
// MODE 1: T1   = X @ Wp2 + bp2 + add(vagg)        -> fp32
// MODE 2: out  = featb + gamma*(X @ Wo + bo)      -> fp32
template <int MODE>
__global__ __launch_bounds__(256) void gemm32(const float* __restrict__ X,
                                              const u32* __restrict__ Wb,
                                              const float* __restrict__ bias,
                                              const float* __restrict__ add,
                                              const float* __restrict__ featb,
                                              const float* __restrict__ gammap,
                                              float* __restrict__ outv) {
    __shared__ u32 Ws[DIM * DIM / 2];   // 32 KB packed bf16 pairs, [c][d/2]
    __shared__ float Xs[8 * DIM];       // 4 KB
    __shared__ float bs[DIM];
    int tid = threadIdx.x;
    {
        const uint4* src = (const uint4*)Wb;
        uint4* dst = (uint4*)Ws;
        for (int i = tid; i < DIM * DIM / 8; i += 256) dst[i] = src[i];
    }
    if (tid < 128) bs[tid] = bias[tid];
    float gamma = 0.f;
    if (MODE == 2) gamma = *gammap;

    int rowBase = blockIdx.x * 32;
    int d4 = (tid & 31) * 4;
    int row = tid >> 5;  // 0..7

    for (int it = 0; it < 4; ++it) {
        int r0 = rowBase + it * 8;
        __syncthreads();
        ((float4*)Xs)[tid] = ((const float4*)(X + (size_t)r0 * DIM))[tid];
        __syncthreads();

        float a0 = bs[d4], a1 = bs[d4 + 1], a2 = bs[d4 + 2], a3 = bs[d4 + 3];
        const float* xr = &Xs[row * DIM];
#pragma unroll 8
        for (int c = 0; c < DIM; ++c) {
            float x = xr[c];
            uint2 w = *(const uint2*)&Ws[c * (DIM / 2) + (d4 >> 1)];
            a0 = fmaf(x, __uint_as_float(w.x << 16), a0);
            a1 = fmaf(x, __uint_as_float(w.x & 0xFFFF0000u), a1);
            a2 = fmaf(x, __uint_as_float(w.y << 16), a2);
            a3 = fmaf(x, __uint_as_float(w.y & 0xFFFF0000u), a3);
        }
        size_t off = (size_t)(r0 + row) * DIM + d4;
        if (MODE == 1) {
            float4 ad = *(const float4*)(add + off);
            a0 += ad.x; a1 += ad.y; a2 += ad.z; a3 += ad.w;
        }
        if (MODE == 2) {
            float4 fb = *(const float4*)(featb + off);
            a0 = fmaf(gamma, a0, fb.x);
            a1 = fmaf(gamma, a1, fb.y);
            a2 = fmaf(gamma, a2, fb.z);
            a3 = fmaf(gamma, a3, fb.w);
        }
        *(float4*)(outv + off) = make_float4(a0, a1, a2, a3);
    }
}

// ---------------------------------------------------------------- stage C
// One wave per point. h kept entirely in REGISTERS (h_lo/h_hi[16], constant-
// indexed via full unroll): no LDS -> no occupancy cap, no ds-ops in the
// serial per-k chain. Loop2 fully unrolled: all 32 coalesced Vf gathers
// depend only on myidx (known upfront) -> issued while softmax completes.
__global__ __launch_bounds__(256, 5) void stage_c(const float4* __restrict__ pts,
                                               const int* __restrict__ idx16,
                                               const float* __restrict__ sK,
                                               const float* __restrict__ w2,
                                               const float* __restrict__ Wp1,
                                               const float* __restrict__ bp1,
                                               const float* __restrict__ Vf,
                                               float* __restrict__ vagg,
                                               float* __restrict__ hbar) {
    int wavein = threadIdx.x >> 6;
    int lid = threadIdx.x & 63;
    int p = blockIdx.x * 4 + wavein;
    int b = p >> 13;
    float4 me = pts[p];

    float wx_lo = Wp1[lid],        wx_hi = Wp1[64 + lid];
    float wy_lo = Wp1[128 + lid],  wy_hi = Wp1[192 + lid];
    float wz_lo = Wp1[256 + lid],  wz_hi = Wp1[320 + lid];
    float bl    = bp1[lid],        bh    = bp1[64 + lid];
    float w2l   = w2[lid],         w2h   = w2[64 + lid];

    int myidx = idx16[p * KNN + (lid & 15)];
    float h_lo[KNN], h_hi[KNN];
    float sc = -INFINITY;

#pragma unroll
    for (int k = 0; k < KNN; ++k) {
        int j = __shfl(myidx, k);
        int g = b * NPTS + j;
        float4 nb = pts[g];
        float rx = me.x - nb.x, ry = me.y - nb.y, rz = me.z - nb.z;
        float hl = fmaxf(0.f, fmaf(rx, wx_lo, fmaf(ry, wy_lo, fmaf(rz, wz_lo, bl))));
        float hh = fmaxf(0.f, fmaf(rx, wx_hi, fmaf(ry, wy_hi, fmaf(rz, wz_hi, bh))));
        h_lo[k] = hl;
        h_hi[k] = hh;
        float s = fmaf(hl, w2l, hh * w2h);
#pragma unroll
        for (int m = 32; m >= 1; m >>= 1) s += __shfl_xor(s, m);
        float score = s - sK[g];
        if (lid == k) sc = score;
    }
    float mx = sc;
#pragma unroll
    for (int m = 8; m >= 1; m >>= 1) mx = fmaxf(mx, __shfl_xor(mx, m));
    float e = (lid < 16) ? __expf(sc - mx) : 0.f;
    float ssum = e;
#pragma unroll
    for (int m = 8; m >= 1; m >>= 1) ssum += __shfl_xor(ssum, m);
    float a = e / ssum;

    float acc_lo = 0.f, acc_hi = 0.f, hb_lo = 0.f, hb_hi = 0.f;
#pragma unroll
    for (int k = 0; k < KNN; ++k) {
        float ak = __shfl(a, k);
        int j = __shfl(myidx, k);
        size_t g = (size_t)(b * NPTS + j) * DIM;
        acc_lo = fmaf(ak, Vf[g + lid], acc_lo);
        acc_hi = fmaf(ak, Vf[g + 64 + lid], acc_hi);
        hb_lo = fmaf(ak, h_lo[k], hb_lo);
        hb_hi = fmaf(ak, h_hi[k], hb_hi);
    }
    size_t o = (size_t)p * DIM;
    vagg[o + lid] = acc_lo;
    vagg[o + 64 + lid] = acc_hi;
    hbar[o + lid] = hb_lo;
    hbar[o + 64 + lid] = hb_hi;
}

// ---------------------------------------------------------------- launcher
extern "C" void kernel_launch(void* const* d_in, const int* in_sizes, int n_in,
                              void* d_out, int out_size, void* d_ws, size_t ws_size,
                              hipStream_t stream) {
    const float* xyz   = (const float*)d_in[0];
    const float* feat  = (const float*)d_in[1];
    // d_in[2]=Wq, d_in[3]=bq, d_in[5]=bk: provably irrelevant (softmax shift-invariance)
    const float* Wk    = (const float*)d_in[4];
    const float* Wv    = (const float*)d_in[6];
    const float* bv    = (const float*)d_in[7];
    const float* Wp1   = (const float*)d_in[8];
    const float* bp1   = (const float*)d_in[9];
    const float* Wp2   = (const float*)d_in[10];
    const float* bp2   = (const float*)d_in[11];
    const float* Wo    = (const float*)d_in[12];
    const float* bo    = (const float*)d_in[13];
    const float* gamma = (const float*)d_in[14];
    float* out = (float*)d_out;

    char* ws = (char*)d_ws;
    const size_t KB = 1024, MB = 1024 * 1024;
    float*  wk    = (float*)(ws + 0);                // 512 B
    float*  w2    = (float*)(ws + 4 * KB);           // 512 B
    float4* pts   = (float4*)(ws + 16 * KB);         // 512 KB
    float*  sKv   = (float*)(ws + 544 * KB);         // 128 KB
    u32*    Wb    = (u32*)(ws + 688 * KB);           // 96 KB (Wv|Wp2|Wo bf16)
    float*  Tq    = (float*)(ws + 1 * MB);           // 128 KB (16th-of-kept bound)
    // dl16q (8 MB) aliases the part16 region: dead before partial writes part16.
    float*  dl16q = (float*)(ws + 5 * MB);           // 8 MB (NROWS x 64 window dists)
    unsigned short* part16 = (unsigned short*)(ws + 5 * MB); // 16 MB, query-major, dead after merge
    float*  vagg  = (float*)(ws + 5 * MB);           // 16 MB, aliases dead part16
    float*  hbarp = (float*)(ws + 21 * MB);          // 16 MB
    int*    idx16 = (int*)(ws + 37 * MB);            // 2 MB
    float*  Vf    = (float*)(ws + 39 * MB);          // 16 MB, dead after stage_c
    float*  T1    = (float*)(ws + 39 * MB);          // aliases Vf  (total 55 MB)

    prep_weights<<<1, 256, 0, stream>>>(Wk, Wp2, wk, w2);
    conv_weights<<<96, 256, 0, stream>>>(Wv, Wp2, Wo, Wb);
    prep_points<<<NROWS / 4, 256, 0, stream>>>(xyz, feat, wk, pts, sKv);
    gemm32<0><<<1024, 256, 0, stream>>>(feat, Wb, bv, nullptr, nullptr, nullptr, Vf);
    knn_limpass<<<dim3(NROWS / 256, NWIN), 256, 0, stream>>>(pts, dl16q);
    bound_merge<<<NROWS / 4, 256, 0, stream>>>(dl16q, Tq);
    knn_partial<<<dim3(NROWS / 256, SPLITS), 256, 0, stream>>>(pts, Tq, part16);
    knn_merge<<<NROWS / 4, 256, 0, stream>>>(pts, part16, idx16);
    stage_c<<<NROWS / 4, 256, 0, stream>>>(pts, idx16, sKv, w2, Wp1, bp1, Vf, vagg, hbarp);
    gemm32<1><<<1024, 256, 0, stream>>>(hbarp, Wb + 8192, bp2, vagg, nullptr, nullptr, T1);
    gemm32<2><<<1024, 256, 0, stream>>>(T1, Wb + 16384, bo, nullptr, feat, gamma, out);
}

// Round 12
// 463.184 us; speedup vs baseline: 1.0615x; 1.0615x over previous
//
#include <hip/hip_runtime.h>
#include <hip/hip_bf16.h>

#define BATCH 4
#define NPTS  8192
#define DIM   128
#define KNN   16
#define NROWS (BATCH * NPTS)   // 32768

#define SPLITS 16
#define RANGE  512             // candidates per split
#define TILE   256             // candidates per drain granule
#define LWIN   512             // limpass window width
#define NWIN   4               // limpass windows (NWIN*LWIN = 2048 cands per bound)

using u64  = unsigned long long;
using u32  = unsigned int;

__device__ __forceinline__ unsigned short f2bf(float f) {
    u32 u = __float_as_uint(f);
    u32 r = (u + 0x7FFFu + ((u >> 16) & 1u)) >> 16;  // RTNE
    return (unsigned short)r;
}
// monotone float -> uint mapping (handles negatives, e.g. self-distance ~ -1e-7)
__device__ __forceinline__ u32 fordkey(float f) {
    u32 u = __float_as_uint(f);
    return (u & 0x80000000u) ? ~u : (u | 0x80000000u);
}
// exact inverse of fordkey
__device__ __forceinline__ float invkey(u32 k) {
    u32 u = (k & 0x80000000u) ? (k & 0x7FFFFFFFu) : ~k;
    return __uint_as_float(u);
}

// u32 chain: compiles to v_min_u32/v_max_u32 pairs (2 VALU/step, 32 total)
__device__ __forceinline__ void insert16u(u32 key, u32* ks) {
    if (key < ks[15]) {
#pragma unroll
        for (int t = 0; t < 16; ++t) {
            u32 lo = key < ks[t] ? key : ks[t];
            u32 hi = key < ks[t] ? ks[t] : key;
            ks[t] = lo;
            key = hi;
        }
    }
}

// exact numpy fp32 op order: (sq_i + sq_j) - 2*((xx+yy)+zz)   [proven in R2]
__device__ __forceinline__ float pdist(float4 me, float4 c) {
    float dot = __fadd_rn(__fadd_rn(__fmul_rn(me.x, c.x), __fmul_rn(me.y, c.y)),
                          __fmul_rn(me.z, c.z));
    return __fsub_rn(__fadd_rn(me.w, c.w), __fmul_rn(2.0f, dot));
}

// ---------------------------------------------------------------- weights prep
__global__ __launch_bounds__(256) void prep_weights(const float* __restrict__ Wk,
                                                    const float* __restrict__ Wp2,
                                                    float* __restrict__ wk,
                                                    float* __restrict__ w2) {
    int tid = threadIdx.x;
    int c = tid & 127;
    const float* src = (tid < 128) ? Wk : Wp2;
    float s = 0.f;
    for (int d = 0; d < DIM; ++d) s += src[c * DIM + d];
    if (tid < 128) wk[c] = s;
    else           w2[c] = s;
}

// convert Wv / Wp2 / Wo to packed bf16 pairs, once (L2-resident afterwards)
__global__ __launch_bounds__(256) void conv_weights(const float* __restrict__ Wv,
                                                    const float* __restrict__ Wp2,
                                                    const float* __restrict__ Wo,
                                                    u32* __restrict__ Wb) {
    int i = blockIdx.x * 256 + threadIdx.x;   // 0 .. 3*8192-1
    int which = i >> 13, off = i & 8191;
    const float* W = (which == 0) ? Wv : (which == 1 ? Wp2 : Wo);
    float2 w = ((const float2*)W)[off];
    Wb[i] = (u32)f2bf(w.x) | ((u32)f2bf(w.y) << 16);
}

// ---------------------------------------------------------------- points prep
__global__ __launch_bounds__(256) void prep_points(const float* __restrict__ xyz,
                                                   const float* __restrict__ feat,
                                                   const float* __restrict__ wk,
                                                   float4* __restrict__ pts,
                                                   float* __restrict__ sK) {
    int lid = threadIdx.x & 63;
    int p = blockIdx.x * 4 + (threadIdx.x >> 6);
    float f_lo = feat[(size_t)p * DIM + lid];
    float f_hi = feat[(size_t)p * DIM + 64 + lid];
    float s = fmaf(f_lo, wk[lid], f_hi * wk[64 + lid]);
#pragma unroll
    for (int m = 32; m >= 1; m >>= 1) s += __shfl_xor(s, m);
    if (lid == 0) {
        float x = xyz[p * 3 + 0];
        float y = xyz[p * 3 + 1];
        float z = xyz[p * 3 + 2];
        float sq = __fadd_rn(__fadd_rn(__fmul_rn(x, x), __fmul_rn(y, y)), __fmul_rn(z, z));
        pts[p] = make_float4(x, y, z, sq);
        sK[p] = s;
    }
}

// ---------------------------------------------------------------- KNN limpass
// Per query q and window y: 16 kept approx distances over the 512 candidates
// [y*512,(y+1)*512) of q's batch -> dl16q[q*64 + y*16 ..] (UNSORTED).
// Top-16 as FOUR independent sorted-4 chains (8 ops/fire vs 32) -- R9 win.
// LDS-STAGED tile (R11 lesson: limpass drains fire ~70x/query; divergent
// global re-reads in the drain pay ~200cy L2 latency exec-mask-serialized,
// +40us regression -- LDS staging is required HERE, unlike partial whose
// drains are rare).
__global__ __launch_bounds__(256) void knn_limpass(const float4* __restrict__ pts,
                                                   float* __restrict__ dl16q) {
    __shared__ float4 tile[256];                   // 4 KB, s-form (x,y,z,-w/2)
    int y = blockIdx.y;
    int wavein = threadIdx.x >> 6, lane = threadIdx.x & 63;
    int q = blockIdx.x * 256 + wavein * 64 + lane;
    int b = blockIdx.x >> 5;   // 256 queries/block, 8192/batch -> provably uniform
    float4 me = pts[q];

    float c0[4], c1[4], c2[4], c3[4];
#pragma unroll
    for (int t = 0; t < 4; ++t) { c0[t] = INFINITY; c1[t] = INFINITY;
                                  c2[t] = INFINITY; c3[t] = INFINITY; }
    float lim = INFINITY;
    float A = -INFINITY;

#define INS4(CH, DV)                                                          \
    if ((DV) < CH[3]) {                                                       \
        float dd_ = (DV);                                                     \
        _Pragma("unroll")                                                     \
        for (int t_ = 0; t_ < 4; ++t_) {                                      \
            float lo_ = fminf(dd_, CH[t_]);                                   \
            float hi_ = fmaxf(dd_, CH[t_]);                                   \
            CH[t_] = lo_; dd_ = hi_;                                          \
        }                                                                     \
    }

    for (int tb = 0; tb < LWIN / 256; ++tb) {
        __syncthreads();
        {
            float4 c = pts[b * NPTS + y * LWIN + tb * 256 + threadIdx.x];
            tile[threadIdx.x] = make_float4(c.x, c.y, c.z, -0.5f * c.w);
        }
        __syncthreads();

        int cstart = 0;
        if (tb == 0) {
            // warmup: first 32 candidates direct into chains (jj&3 compile-time)
#pragma unroll
            for (int jj = 0; jj < 32; ++jj) {
                float4 c = tile[jj];
                float s = fmaf(me.x, c.x, fmaf(me.y, c.y, fmaf(me.z, c.z, c.w)));
                float d = fmaf(-2.0f, s, me.w);
                if ((jj & 3) == 0)      { INS4(c0, d); }
                else if ((jj & 3) == 1) { INS4(c1, d); }
                else if ((jj & 3) == 2) { INS4(c2, d); }
                else                    { INS4(c3, d); }
            }
            lim = fmaxf(fmaxf(c0[3], c1[3]), fmaxf(c2[3], c3[3]));
            A = 0.5f * (me.w - lim);
            cstart = 32;
        }
        for (int cw = cstart; cw < 256; cw += 32) {
            u32 mask = 0;
#pragma unroll
            for (int jj = 0; jj < 32; ++jj) {
                float4 c = tile[cw + jj];
                float s = fmaf(me.x, c.x, fmaf(me.y, c.y, fmaf(me.z, c.z, c.w)));
                mask = (mask << 1) | (u32)(s >= A);   // bit (31-jj) <- cand cw+jj
            }
#define POP_INS(CH)                                                           \
            if (mask) {                                                       \
                int pos_ = __builtin_ctz(mask); mask &= mask - 1;             \
                int jj_ = cw + 31 - pos_;                                     \
                float4 c_ = tile[jj_];                                        \
                float s_ = fmaf(me.x, c_.x,                                   \
                            fmaf(me.y, c_.y, fmaf(me.z, c_.z, c_.w)));        \
                float d_ = fmaf(-2.0f, s_, me.w);                             \
                INS4(CH, d_);                                                 \
            }
            while (mask) {
                POP_INS(c0);
                POP_INS(c1);
                POP_INS(c2);
                POP_INS(c3);
            }
#undef POP_INS
            lim = fmaxf(fmaxf(c0[3], c1[3]), fmaxf(c2[3], c3[3]));
            A = 0.5f * (me.w - lim);
        }
    }
#undef INS4
    float4* dst = (float4*)(dl16q + (size_t)q * 64 + y * 16);
    dst[0] = make_float4(c0[0], c0[1], c0[2], c0[3]);
    dst[1] = make_float4(c1[0], c1[1], c1[2], c1[3]);
    dst[2] = make_float4(c2[0], c2[1], c2[2], c2[3]);
    dst[3] = make_float4(c3[0], c3[1], c3[2], c3[3]);
}

// ---------------------------------------------------------------- bound merge
// One wave per query: 64 lanes hold the 4x16 window distances (unsorted);
// 16 rounds of wave-min extraction yield the 16th-of-64-kept (ties only
// inflate the result -> still a valid upper bound on the global 16th-NN).
__global__ __launch_bounds__(256) void bound_merge(const float* __restrict__ dl16q,
                                                   float* __restrict__ Tq) {
    int wavein = threadIdx.x >> 6, lane = threadIdx.x & 63;
    int q = blockIdx.x * 4 + wavein;
    float v = dl16q[(size_t)q * 64 + lane];
    float got = v;
#pragma unroll
    for (int it = 0; it < 16; ++it) {
        float m = v;
#pragma unroll
        for (int s = 32; s >= 1; s >>= 1) m = fminf(m, __shfl_xor(m, s));
        if (v == m) v = INFINITY;   // clear winner(s); ties only over-estimate
        got = m;
    }
    if (lane == 0) Tq[q] = got;
}

// ---------------------------------------------------------------- KNN partial
// grid (128, SPLITS); split r covers [r*512,(r+1)*512). Gate T = 16th-of-kept
// bound (rank ~70) -> survivors ~4-5/lane/split. Bitmask scan with DIRECT
// wave-uniform global reads (R10/R11: L1 broadcasts a same-address wave64
// load as one request; equal to LDS-broadcast here because drains are RARE
// -- no staging, no barriers, no LDS). Drain deferred per 256-granule via
// 8 mask words + skip-empty select chain; drains recompute the same fp
// sequence -> keys bit-identical. ONE query per thread (R6/R7: Q-blocking
// spills). Chain keys u32: top-19 bits of fordkey(d~) | 13-bit idx (merge
// re-ranks exactly). Sentinel 0xFFFFFFFF; gate ratchets via quantization-
// cell upper bound + 1e-4 slop. part16 QUERY-MAJOR; 0xFFFF empty.
__global__ __launch_bounds__(256) void knn_partial(const float4* __restrict__ pts,
                                                   const float* __restrict__ Tq,
                                                   unsigned short* __restrict__ part16) {
    int r = blockIdx.y;
    int wavein = threadIdx.x >> 6, lane = threadIdx.x & 63;
    int q = blockIdx.x * 256 + wavein * 64 + lane;
    int b = blockIdx.x >> 5;   // 256 q/block, 32 blocks/batch -> uniform (== q>>13)
    float4 me = pts[q];
    const float4* sp = pts + b * NPTS + r * RANGE;    // wave-uniform split base

    float gate_d = Tq[q] + 2.0e-4f;                   // admits all true 16-NN
    u32 kk[16];
#pragma unroll
    for (int t = 0; t < 16; ++t) kk[t] = 0xFFFFFFFFu;
    float A = 0.5f * (me.w - gate_d) - 1.0e-4f;       // s >= A <=> d~ <= gate_d (+slop)

    for (int tb = 0; tb < RANGE / TILE; ++tb) {
        int jb = r * RANGE + tb * TILE;
        const float4* tp = sp + tb * TILE;

        u32 m[8];
#pragma unroll
        for (int w = 0; w < 8; ++w) {
            u32 mask = 0;
#pragma unroll
            for (int jj = 0; jj < 32; ++jj) {
                float4 c = tp[w * 32 + jj];
                float cw = -0.5f * c.w;
                float s = fmaf(me.x, c.x, fmaf(me.y, c.y, fmaf(me.z, c.z, cw)));
                mask = (mask << 1) | (u32)(s >= A);   // bit (31-jj) <- cand w*32+jj
            }
            m[w] = mask;
        }
        int cnt = __popc(m[0]) + __popc(m[1]) + __popc(m[2]) + __popc(m[3]) +
                  __popc(m[4]) + __popc(m[5]) + __popc(m[6]) + __popc(m[7]);

        u32 cur = m[0];
        int w = 0;
        for (int i = 0; i < cnt; ++i) {               // exec-masked to wave-max
            while (cur == 0) {                        // skip empty words (<=7 total)
                ++w;
                cur = (w == 1) ? m[1] : (w == 2) ? m[2] : (w == 3) ? m[3] :
                      (w == 4) ? m[4] : (w == 5) ? m[5] : (w == 6) ? m[6] : m[7];
            }
            int pos = __builtin_ctz(cur);
            cur &= cur - 1;
            int jj = (w << 5) + (31 - pos);
            float4 c = tp[jj];
            float cw = -0.5f * c.w;
            float s = fmaf(me.x, c.x, fmaf(me.y, c.y, fmaf(me.z, c.z, cw)));
            float dt = fmaf(-2.0f, s, me.w);           // same fp sequence as scan
            u32 key = (fordkey(dt) & 0xFFFFE000u) | (u32)(jb + jj);
            insert16u(key, kk);
        }
        // ratchet: quantization-cell upper bound of current 16th + slop.
        // sentinel (0xFFFFFFFF) -> invkey = NaN -> comparison false -> no-op.
        float nl = invkey((kk[15] & 0xFFFFE000u) | 0x1FFFu) + 1.0e-4f;
        gate_d = (nl < gate_d) ? nl : gate_d;          // monotone ratchet
        A = 0.5f * (me.w - gate_d) - 1.0e-4f;
    }
    u32* dst = (u32*)(part16 + (size_t)q * 256 + r * 16);
#pragma unroll
    for (int t = 0; t < 8; ++t) {
        u32 a = kk[2 * t], c = kk[2 * t + 1];
        u32 i0 = (a == 0xFFFFFFFFu) ? 0xFFFFu : (a & 0x1FFFu);
        u32 i1 = (c == 0xFFFFFFFFu) ? 0xFFFFu : (c & 0x1FFFu);
        dst[t] = i0 | (i1 << 16);
    }
}

// ---------------------------------------------------------------- KNN merge
// One WAVE per query. Keys are (hi=fordkey(exact d), lo=idx) pairs kept in
// separate u32 regs. Extraction rounds reduce ONLY the hi word (6 x {shfl_xor
// + v_min_u32}); the winner's lo is fetched with one shuffle when the hi-min
// is unique (ballot popcount == 1, the ~always case, wave-uniform branch) or
// via a second masked u32 reduce on a genuine distance tie. Selection order
// is exactly (d, idx)-lexicographic == the serial exact-key merge.
__global__ __launch_bounds__(256) void knn_merge(const float4* __restrict__ pts,
                                                 const unsigned short* __restrict__ part16,
                                                 int* __restrict__ idx16) {
    int wavein = threadIdx.x >> 6, lane = threadIdx.x & 63;
    int q = blockIdx.x * 4 + wavein;
    int b = q >> 13;
    float4 me = pts[q];
    ushort4 e = *(const ushort4*)(part16 + (size_t)q * 256 + lane * 4);
    u64 k0, k1, k2, k3;
    {
        u32 id, ida;
        id = e.x; ida = (id != 0xFFFFu) ? id : 0u;
        k0 = (id != 0xFFFFu) ? (((u64)fordkey(pdist(me, pts[b * NPTS + ida])) << 32) | id) : ~0ull;
        id = e.y; ida = (id != 0xFFFFu) ? id : 0u;
        k1 = (id != 0xFFFFu) ? (((u64)fordkey(pdist(me, pts[b * NPTS + ida])) << 32) | id) : ~0ull;
        id = e.z; ida = (id != 0xFFFFu) ? id : 0u;
        k2 = (id != 0xFFFFu) ? (((u64)fordkey(pdist(me, pts[b * NPTS + ida])) << 32) | id) : ~0ull;
        id = e.w; ida = (id != 0xFFFFu) ? id : 0u;
        k3 = (id != 0xFFFFu) ? (((u64)fordkey(pdist(me, pts[b * NPTS + ida])) << 32) | id) : ~0ull;
    }
    // sort4 (network: (0,1)(2,3)(0,2)(1,3)(1,2)) on full u64 keys (reg-only)
    u64 t;
    if (k1 < k0) { t = k0; k0 = k1; k1 = t; }
    if (k3 < k2) { t = k2; k2 = k3; k3 = t; }
    if (k2 < k0) { t = k0; k0 = k2; k2 = t; }
    if (k3 < k1) { t = k1; k1 = k3; k3 = t; }
    if (k2 < k1) { t = k1; k1 = k2; k2 = t; }

    u32 curh = (u32)(k0 >> 32), curl = (u32)k0;
    int head = 0;
    u32 gotl = 0;
#pragma unroll
    for (int it = 0; it < 16; ++it) {
        u32 mh = curh;
#pragma unroll
        for (int s = 32; s >= 1; s >>= 1) {
            u32 o = __shfl_xor(mh, s);
            mh = (o < mh) ? o : mh;
        }
        u64 bal = __ballot(curh == mh);
        u32 wlo;
        if (__builtin_popcountll(bal) == 1) {         // unique hi-min (~always)
            int wl = __builtin_ctzll(bal);
            wlo = __shfl(curl, wl);
        } else {                                      // exact-distance tie: min idx
            u32 cand = (curh == mh) ? curl : 0xFFFFFFFFu;
#pragma unroll
            for (int s = 32; s >= 1; s >>= 1) {
                u32 o = __shfl_xor(cand, s);
                cand = (o < cand) ? o : cand;
            }
            wlo = cand;
        }
        if (curh == mh && curl == wlo) {              // winner advances its head
            head++;
            u64 nx = (head == 1) ? k1 : (head == 2) ? k2 : (head == 3) ? k3 : ~0ull;
            curh = (u32)(nx >> 32);
            curl = (u32)nx;
        }
        if (lane == it) gotl = wlo;
    }
    if (lane < 16) idx16[q * KNN + lane] = (int)gotl;
}

// ---------------------------------------------------------------- GEMM 32-row
// X fp32, W pre-packed bf16 pairs (global, staged to LDS), accum fp32.
// MODE 0: Vf   = X @ Wv + bv                      -> fp32
// MODE 1: T1   = X @ Wp2 + bp2 + add(vagg)        -> fp32
// MODE 2: out  = featb + gamma*(X @ Wo + bo)      -> fp32
template <int MODE>
__global__ __launch_bounds__(256) void gemm32(const float* __restrict__ X,
                                              const u32* __restrict__ Wb,
                                              const float* __restrict__ bias,
                                              const float* __restrict__ add,
                                              const float* __restrict__ featb,
                                              const float* __restrict__ gammap,
                                              float* __restrict__ outv) {
    __shared__ u32 Ws[DIM * DIM / 2];   // 32 KB packed bf16 pairs, [c][d/2]
    __shared__ float Xs[8 * DIM];       // 4 KB
    __shared__ float bs[DIM];
    int tid = threadIdx.x;
    {
        const uint4* src = (const uint4*)Wb;
        uint4* dst = (uint4*)Ws;
        for (int i = tid; i < DIM * DIM / 8; i += 256) dst[i] = src[i];
    }
    if (tid < 128) bs[tid] = bias[tid];
    float gamma = 0.f;
    if (MODE == 2) gamma = *gammap;

    int rowBase = blockIdx.x * 32;
    int d4 = (tid & 31) * 4;
    int row = tid >> 5;  // 0..7

    for (int it = 0; it < 4; ++it) {
        int r0 = rowBase + it * 8;
        __syncthreads();
        ((float4*)Xs)[tid] = ((const float4*)(X + (size_t)r0 * DIM))[tid];
        __syncthreads();

        float a0 = bs[d4], a1 = bs[d4 + 1], a2 = bs[d4 + 2], a3 = bs[d4 + 3];
        const float* xr = &Xs[row * DIM];
#pragma unroll 8
        for (int c = 0; c < DIM; ++c) {
            float x = xr[c];
            uint2 w = *(const uint2*)&Ws[c * (DIM / 2) + (d4 >> 1)];
            a0 = fmaf(x, __uint_as_float(w.x << 16), a0);
            a1 = fmaf(x, __uint_as_float(w.x & 0xFFFF0000u), a1);
            a2 = fmaf(x, __uint_as_float(w.y << 16), a2);
            a3 = fmaf(x, __uint_as_float(w.y & 0xFFFF0000u), a3);
        }
        size_t off = (size_t)(r0 + row) * DIM + d4;
        if (MODE == 1) {
            float4 ad = *(const float4*)(add + off);
            a0 += ad.x; a1 += ad.y; a2 += ad.z; a3 += ad.w;
        }
        if (MODE == 2) {
            float4 fb = *(const float4*)(featb + off);
            a0 = fmaf(gamma, a0, fb.x);
            a1 = fmaf(gamma, a1, fb.y);
            a2 = fmaf(gamma, a2, fb.z);
            a3 = fmaf(gamma, a3, fb.w);
        }
        *(float4*)(outv + off) = make_float4(a0, a1, a2, a3);
    }
}

// ---------------------------------------------------------------- stage C
// One wave per point. h kept entirely in REGISTERS (h_lo/h_hi[16], constant-
// indexed via full unroll): no LDS -> no occupancy cap, no ds-ops in the
// serial per-k chain. Loop2 fully unrolled: all 32 coalesced Vf gathers
// depend only on myidx (known upfront) -> issued while softmax completes.
__global__ __launch_bounds__(256, 5) void stage_c(const float4* __restrict__ pts,
                                               const int* __restrict__ idx16,
                                               const float* __restrict__ sK,
                                               const float* __restrict__ w2,
                                               const float* __restrict__ Wp1,
                                               const float* __restrict__ bp1,
                                               const float* __restrict__ Vf,
                                               float* __restrict__ vagg,
                                               float* __restrict__ hbar) {
    int wavein = threadIdx.x >> 6;
    int lid = threadIdx.x & 63;
    int p = blockIdx.x * 4 + wavein;
    int b = p >> 13;
    float4 me = pts[p];

    float wx_lo = Wp1[lid],        wx_hi = Wp1[64 + lid];
    float wy_lo = Wp1[128 + lid],  wy_hi = Wp1[192 + lid];
    float wz_lo = Wp1[256 + lid],  wz_hi = Wp1[320 + lid];
    float bl    = bp1[lid],        bh    = bp1[64 + lid];
    float w2l   = w2[lid],         w2h   = w2[64 + lid];

    int myidx = idx16[p * KNN + (lid & 15)];
    float h_lo[KNN], h_hi[KNN];
    float sc = -INFINITY;

#pragma unroll
    for (int k = 0; k < KNN; ++k) {
        int j = __shfl(myidx, k);
        int g = b * NPTS + j;
        float4 nb = pts[g];
        float rx = me.x - nb.x, ry = me.y - nb.y, rz = me.z - nb.z;
        float hl = fmaxf(0.f, fmaf(rx, wx_lo, fmaf(ry, wy_lo, fmaf(rz, wz_lo, bl))));
        float hh = fmaxf(0.f, fmaf(rx, wx_hi, fmaf(ry, wy_hi, fmaf(rz, wz_hi, bh))));
        h_lo[k] = hl;
        h_hi[k] = hh;
        float s = fmaf(hl, w2l, hh * w2h);
#pragma unroll
        for (int m = 32; m >= 1; m >>= 1) s += __shfl_xor(s, m);
        float score = s - sK[g];
        if (lid == k) sc = score;
    }
    float mx = sc;
#pragma unroll
    for (int m = 8; m >= 1; m >>= 1) mx = fmaxf(mx, __shfl_xor(mx, m));
    float e = (lid < 16) ? __expf(sc - mx) : 0.f;
    float ssum = e;
#pragma unroll
    for (int m = 8; m >= 1; m >>= 1) ssum += __shfl_xor(ssum, m);
    float a = e / ssum;

    float acc_lo = 0.f, acc_hi = 0.f, hb_lo = 0.f, hb_hi = 0.f;
#pragma unroll
    for (int k = 0; k < KNN; ++k) {
        float ak = __shfl(a, k);
        int j = __shfl(myidx, k);
        size_t g = (size_t)(b * NPTS + j) * DIM;
        acc_lo = fmaf(ak, Vf[g + lid], acc_lo);
        acc_hi = fmaf(ak, Vf[g + 64 + lid], acc_hi);
        hb_lo = fmaf(ak, h_lo[k], hb_lo);
        hb_hi = fmaf(ak, h_hi[k], hb_hi);
    }
    size_t o = (size_t)p * DIM;
    vagg[o + lid] = acc_lo;
    vagg[o + 64 + lid] = acc_hi;
    hbar[o + lid] = hb_lo;
    hbar[o + 64 + lid] = hb_hi;
}

// ---------------------------------------------------------------- launcher
extern "C" void kernel_launch(void* const* d_in, const int* in_sizes, int n_in,
                              void* d_out, int out_size, void* d_ws, size_t ws_size,
                              hipStream_t stream) {
    const float* xyz   = (const float*)d_in[0];
    const float* feat  = (const float*)d_in[1];
    // d_in[2]=Wq, d_in[3]=bq, d_in[5]=bk: provably irrelevant (softmax shift-invariance)
    const float* Wk    = (const float*)d_in[4];
    const float* Wv    = (const float*)d_in[6];
    const float* bv    = (const float*)d_in[7];
    const float* Wp1   = (const float*)d_in[8];
    const float* bp1   = (const float*)d_in[9];
    const float* Wp2   = (const float*)d_in[10];
    const float* bp2   = (const float*)d_in[11];
    const float* Wo    = (const float*)d_in[12];
    const float* bo    = (const float*)d_in[13];
    const float* gamma = (const float*)d_in[14];
    float* out = (float*)d_out;

    char* ws = (char*)d_ws;
    const size_t KB = 1024, MB = 1024 * 1024;
    float*  wk    = (float*)(ws + 0);                // 512 B
    float*  w2    = (float*)(ws + 4 * KB);           // 512 B
    float4* pts   = (float4*)(ws + 16 * KB);         // 512 KB
    float*  sKv   = (float*)(ws + 544 * KB);         // 128 KB
    u32*    Wb    = (u32*)(ws + 688 * KB);           // 96 KB (Wv|Wp2|Wo bf16)
    float*  Tq    = (float*)(ws + 1 * MB);           // 128 KB (16th-of-kept bound)
    // dl16q (8 MB) aliases the part16 region: dead before partial writes part16.
    float*  dl16q = (float*)(ws + 5 * MB);           // 8 MB (NROWS x 64 window dists)
    unsigned short* part16 = (unsigned short*)(ws + 5 * MB); // 16 MB, query-major, dead after merge
    float*  vagg  = (float*)(ws + 5 * MB);           // 16 MB, aliases dead part16
    float*  hbarp = (float*)(ws + 21 * MB);          // 16 MB
    int*    idx16 = (int*)(ws + 37 * MB);            // 2 MB
    float*  Vf    = (float*)(ws + 39 * MB);          // 16 MB, dead after stage_c
    float*  T1    = (float*)(ws + 39 * MB);          // aliases Vf  (total 55 MB)

    prep_weights<<<1, 256, 0, stream>>>(Wk, Wp2, wk, w2);
    conv_weights<<<96, 256, 0, stream>>>(Wv, Wp2, Wo, Wb);
    prep_points<<<NROWS / 4, 256, 0, stream>>>(xyz, feat, wk, pts, sKv);
    gemm32<0><<<1024, 256, 0, stream>>>(feat, Wb, bv, nullptr, nullptr, nullptr, Vf);
    knn_limpass<<<dim3(NROWS / 256, NWIN), 256, 0, stream>>>(pts, dl16q);
    bound_merge<<<NROWS / 4, 256, 0, stream>>>(dl16q, Tq);
    knn_partial<<<dim3(NROWS / 256, SPLITS), 256, 0, stream>>>(pts, Tq, part16);
    knn_merge<<<NROWS / 4, 256, 0, stream>>>(pts, part16, idx16);
    stage_c<<<NROWS / 4, 256, 0, stream>>>(pts, idx16, sKv, w2, Wp1, bp1, Vf, vagg, hbarp);
    gemm32<1><<<1024, 256, 0, stream>>>(hbarp, Wb + 8192, bp2, vagg, nullptr, nullptr, T1);
    gemm32<2><<<1024, 256, 0, stream>>>(T1, Wb + 16384, bo, nullptr, feat, gamma, out);
}

// Round 13
// 452.794 us; speedup vs baseline: 1.0858x; 1.0229x over previous
//
#include <hip/hip_runtime.h>
#include <hip/hip_bf16.h>

#define BATCH 4
#define NPTS  8192
#define DIM   128
#define KNN   16
#define NROWS (BATCH * NPTS)   // 32768

#define SPLITS 16
#define RANGE  512             // candidates per split
#define TILE   256             // candidates per LDS tile (drain granularity)
#define LWIN   512             // limpass window width
#define NWIN   4               // limpass windows (NWIN*LWIN = 2048 cands per bound)

using u64  = unsigned long long;
using u32  = unsigned int;

__device__ __forceinline__ unsigned short f2bf(float f) {
    u32 u = __float_as_uint(f);
    u32 r = (u + 0x7FFFu + ((u >> 16) & 1u)) >> 16;  // RTNE
    return (unsigned short)r;
}
// monotone float -> uint mapping (handles negatives, e.g. self-distance ~ -1e-7)
__device__ __forceinline__ u32 fordkey(float f) {
    u32 u = __float_as_uint(f);
    return (u & 0x80000000u) ? ~u : (u | 0x80000000u);
}
// exact inverse of fordkey
__device__ __forceinline__ float invkey(u32 k) {
    u32 u = (k & 0x80000000u) ? (k & 0x7FFFFFFFu) : ~k;
    return __uint_as_float(u);
}

// u32 chain: compiles to v_min_u32/v_max_u32 pairs (2 VALU/step, 32 total)
__device__ __forceinline__ void insert16u(u32 key, u32* ks) {
    if (key < ks[15]) {
#pragma unroll
        for (int t = 0; t < 16; ++t) {
            u32 lo = key < ks[t] ? key : ks[t];
            u32 hi = key < ks[t] ? ks[t] : key;
            ks[t] = lo;
            key = hi;
        }
    }
}

// exact numpy fp32 op order: (sq_i + sq_j) - 2*((xx+yy)+zz)   [proven in R2]
__device__ __forceinline__ float pdist(float4 me, float4 c) {
    float dot = __fadd_rn(__fadd_rn(__fmul_rn(me.x, c.x), __fmul_rn(me.y, c.y)),
                          __fmul_rn(me.z, c.z));
    return __fsub_rn(__fadd_rn(me.w, c.w), __fmul_rn(2.0f, dot));
}

// ---------------------------------------------------------------- weights prep
__global__ __launch_bounds__(256) void prep_weights(const float* __restrict__ Wk,
                                                    const float* __restrict__ Wp2,
                                                    float* __restrict__ wk,
                                                    float* __restrict__ w2) {
    int tid = threadIdx.x;
    int c = tid & 127;
    const float* src = (tid < 128) ? Wk : Wp2;
    float s = 0.f;
    for (int d = 0; d < DIM; ++d) s += src[c * DIM + d];
    if (tid < 128) wk[c] = s;
    else           w2[c] = s;
}

// convert Wv / Wp2 / Wo to packed bf16 pairs, once (L2-resident afterwards)
__global__ __launch_bounds__(256) void conv_weights(const float* __restrict__ Wv,
                                                    const float* __restrict__ Wp2,
                                                    const float* __restrict__ Wo,
                                                    u32* __restrict__ Wb) {
    int i = blockIdx.x * 256 + threadIdx.x;   // 0 .. 3*8192-1
    int which = i >> 13, off = i & 8191;
    const float* W = (which == 0) ? Wv : (which == 1 ? Wp2 : Wo);
    float2 w = ((const float2*)W)[off];
    Wb[i] = (u32)f2bf(w.x) | ((u32)f2bf(w.y) << 16);
}

// ---------------------------------------------------------------- points prep
__global__ __launch_bounds__(256) void prep_points(const float* __restrict__ xyz,
                                                   const float* __restrict__ feat,
                                                   const float* __restrict__ wk,
                                                   float4* __restrict__ pts,
                                                   float* __restrict__ sK) {
    int lid = threadIdx.x & 63;
    int p = blockIdx.x * 4 + (threadIdx.x >> 6);
    float f_lo = feat[(size_t)p * DIM + lid];
    float f_hi = feat[(size_t)p * DIM + 64 + lid];
    float s = fmaf(f_lo, wk[lid], f_hi * wk[64 + lid]);
#pragma unroll
    for (int m = 32; m >= 1; m >>= 1) s += __shfl_xor(s, m);
    if (lid == 0) {
        float x = xyz[p * 3 + 0];
        float y = xyz[p * 3 + 1];
        float z = xyz[p * 3 + 2];
        float sq = __fadd_rn(__fadd_rn(__fmul_rn(x, x), __fmul_rn(y, y)), __fmul_rn(z, z));
        pts[p] = make_float4(x, y, z, sq);
        sK[p] = s;
    }
}

// ---------------------------------------------------------------- KNN limpass
// Per query q and window y: 16 kept approx distances over the 512 candidates
// [y*512,(y+1)*512) of q's batch -> dl16q[q*64 + y*16 ..] (UNSORTED).
// Top-16 as FOUR independent sorted-4 chains (8 ops/fire vs 32) -- R9 win.
// LDS-STAGED tile (R11 lesson: limpass drains fire ~70x/query; divergent
// global re-reads in the drain pay ~200cy L2 latency exec-mask-serialized).
__global__ __launch_bounds__(256) void knn_limpass(const float4* __restrict__ pts,
                                                   float* __restrict__ dl16q) {
    __shared__ float4 tile[256];                   // 4 KB, s-form (x,y,z,-w/2)
    int y = blockIdx.y;
    int wavein = threadIdx.x >> 6, lane = threadIdx.x & 63;
    int q = blockIdx.x * 256 + wavein * 64 + lane;
    int b = blockIdx.x >> 5;   // 256 queries/block, 8192/batch -> provably uniform
    float4 me = pts[q];

    float c0[4], c1[4], c2[4], c3[4];
#pragma unroll
    for (int t = 0; t < 4; ++t) { c0[t] = INFINITY; c1[t] = INFINITY;
                                  c2[t] = INFINITY; c3[t] = INFINITY; }
    float lim = INFINITY;
    float A = -INFINITY;

#define INS4(CH, DV)                                                          \
    if ((DV) < CH[3]) {                                                       \
        float dd_ = (DV);                                                     \
        _Pragma("unroll")                                                     \
        for (int t_ = 0; t_ < 4; ++t_) {                                      \
            float lo_ = fminf(dd_, CH[t_]);                                   \
            float hi_ = fmaxf(dd_, CH[t_]);                                   \
            CH[t_] = lo_; dd_ = hi_;                                          \
        }                                                                     \
    }

    for (int tb = 0; tb < LWIN / 256; ++tb) {
        __syncthreads();
        {
            float4 c = pts[b * NPTS + y * LWIN + tb * 256 + threadIdx.x];
            tile[threadIdx.x] = make_float4(c.x, c.y, c.z, -0.5f * c.w);
        }
        __syncthreads();

        int cstart = 0;
        if (tb == 0) {
            // warmup: first 32 candidates direct into chains (jj&3 compile-time)
#pragma unroll
            for (int jj = 0; jj < 32; ++jj) {
                float4 c = tile[jj];
                float s = fmaf(me.x, c.x, fmaf(me.y, c.y, fmaf(me.z, c.z, c.w)));
                float d = fmaf(-2.0f, s, me.w);
                if ((jj & 3) == 0)      { INS4(c0, d); }
                else if ((jj & 3) == 1) { INS4(c1, d); }
                else if ((jj & 3) == 2) { INS4(c2, d); }
                else                    { INS4(c3, d); }
            }
            lim = fmaxf(fmaxf(c0[3], c1[3]), fmaxf(c2[3], c3[3]));
            A = 0.5f * (me.w - lim);
            cstart = 32;
        }
        for (int cw = cstart; cw < 256; cw += 32) {
            u32 mask = 0;
#pragma unroll
            for (int jj = 0; jj < 32; ++jj) {
                float4 c = tile[cw + jj];
                float s = fmaf(me.x, c.x, fmaf(me.y, c.y, fmaf(me.z, c.z, c.w)));
                mask = (mask << 1) | (u32)(s >= A);   // bit (31-jj) <- cand cw+jj
            }
#define POP_INS(CH)                                                           \
            if (mask) {                                                       \
                int pos_ = __builtin_ctz(mask); mask &= mask - 1;             \
                int jj_ = cw + 31 - pos_;                                     \
                float4 c_ = tile[jj_];                                        \
                float s_ = fmaf(me.x, c_.x,                                   \
                            fmaf(me.y, c_.y, fmaf(me.z, c_.z, c_.w)));        \
                float d_ = fmaf(-2.0f, s_, me.w);                             \
                INS4(CH, d_);                                                 \
            }
            while (mask) {
                POP_INS(c0);
                POP_INS(c1);
                POP_INS(c2);
                POP_INS(c3);
            }
#undef POP_INS
            lim = fmaxf(fmaxf(c0[3], c1[3]), fmaxf(c2[3], c3[3]));
            A = 0.5f * (me.w - lim);
        }
    }
#undef INS4
    float4* dst = (float4*)(dl16q + (size_t)q * 64 + y * 16);
    dst[0] = make_float4(c0[0], c0[1], c0[2], c0[3]);
    dst[1] = make_float4(c1[0], c1[1], c1[2], c1[3]);
    dst[2] = make_float4(c2[0], c2[1], c2[2], c2[3]);
    dst[3] = make_float4(c3[0], c3[1], c3[2], c3[3]);
}

// ---------------------------------------------------------------- bound merge
// One wave per query: 64 lanes hold the 4x16 window distances (unsorted);
// 16 rounds of wave-min extraction yield the 16th-of-64-kept (ties only
// inflate the result -> still a valid upper bound on the global 16th-NN).
__global__ __launch_bounds__(256) void bound_merge(const float* __restrict__ dl16q,
                                                   float* __restrict__ Tq) {
    int wavein = threadIdx.x >> 6, lane = threadIdx.x & 63;
    int q = blockIdx.x * 4 + wavein;
    float v = dl16q[(size_t)q * 64 + lane];
    float got = v;
#pragma unroll
    for (int it = 0; it < 16; ++it) {
        float m = v;
#pragma unroll
        for (int s = 32; s >= 1; s >>= 1) m = fminf(m, __shfl_xor(m, s));
        if (v == m) v = INFINITY;   // clear winner(s); ties only over-estimate
        got = m;
    }
    if (lane == 0) Tq[q] = got;
}

// ---------------------------------------------------------------- KNN partial
// grid (128, SPLITS); split r covers [r*RANGE,(r+1)*RANGE). Gate T = 16th-of-
// kept bound (rank ~70) -> survivors ~4-5/lane/split. LDS-staged tile +
// bitmask scan (5 VALU/eval, no stack, no overflow path); drain deferred to
// once per 256-tile via 8 mask words + skip-empty select chain. ONE query
// per thread (R6/R7: Q-blocking spills to scratch). This LDS-staged form is
// the measured-best transport (R8/R9: ~80us, VALUBusy ~85%); direct-global
// (R11/R12) is latency-bound at the same floor but totals worse. Chain keys
// u32: top-19 bits of fordkey(d~) | 13-bit idx (merge re-ranks exactly).
// Sentinel 0xFFFFFFFF; gate ratchets via quantization-cell upper bound +
// 1e-4 slop. part16 QUERY-MAJOR: part16[q*256 + r*16 + t]; 0xFFFF empty.
__global__ __launch_bounds__(256) void knn_partial(const float4* __restrict__ pts,
                                                   const float* __restrict__ Tq,
                                                   unsigned short* __restrict__ part16) {
    __shared__ float4 tile[TILE];                    // 4 KB, s-form
    int r = blockIdx.y;
    int wavein = threadIdx.x >> 6, lane = threadIdx.x & 63;
    int q = blockIdx.x * 256 + wavein * 64 + lane;
    int b = blockIdx.x >> 5;   // 256 q/block, 32 blocks/batch -> uniform (== q>>13)
    float4 me = pts[q];

    float gate_d = Tq[q] + 2.0e-4f;                   // admits all true 16-NN
    u32 kk[16];
#pragma unroll
    for (int t = 0; t < 16; ++t) kk[t] = 0xFFFFFFFFu;
    float A = 0.5f * (me.w - gate_d) - 1.0e-4f;       // s >= A <=> d~ <= gate_d (+slop)

    for (int tb = 0; tb < RANGE / TILE; ++tb) {
        __syncthreads();
        int jb = r * RANGE + tb * TILE;
        {
            float4 c = pts[b * NPTS + jb + threadIdx.x];
            tile[threadIdx.x] = make_float4(c.x, c.y, c.z, -0.5f * c.w);
        }
        __syncthreads();

        u32 m[8];
#pragma unroll
        for (int w = 0; w < 8; ++w) {
            u32 mask = 0;
#pragma unroll
            for (int jj = 0; jj < 32; ++jj) {
                float4 c = tile[w * 32 + jj];
                float s = fmaf(me.x, c.x, fmaf(me.y, c.y, fmaf(me.z, c.z, c.w)));
                mask = (mask << 1) | (u32)(s >= A);   // bit (31-jj) <- cand w*32+jj
            }
            m[w] = mask;
        }
        int cnt = __popc(m[0]) + __popc(m[1]) + __popc(m[2]) + __popc(m[3]) +
                  __popc(m[4]) + __popc(m[5]) + __popc(m[6]) + __popc(m[7]);

        u32 cur = m[0];
        int w = 0;
        for (int i = 0; i < cnt; ++i) {               // exec-masked to wave-max
            while (cur == 0) {                        // skip empty words (<=7 total)
                ++w;
                cur = (w == 1) ? m[1] : (w == 2) ? m[2] : (w == 3) ? m[3] :
                      (w == 4) ? m[4] : (w == 5) ? m[5] : (w == 6) ? m[6] : m[7];
            }
            int pos = __builtin_ctz(cur);
            cur &= cur - 1;
            int jj = (w << 5) + (31 - pos);
            float4 c = tile[jj];
            float s = fmaf(me.x, c.x, fmaf(me.y, c.y, fmaf(me.z, c.z, c.w)));
            float dt = fmaf(-2.0f, s, me.w);           // same fp sequence as scan
            u32 key = (fordkey(dt) & 0xFFFFE000u) | (u32)(jb + jj);
            insert16u(key, kk);
        }
        // ratchet: quantization-cell upper bound of current 16th + slop.
        // sentinel (0xFFFFFFFF) -> invkey = NaN -> comparison false -> no-op.
        float nl = invkey((kk[15] & 0xFFFFE000u) | 0x1FFFu) + 1.0e-4f;
        gate_d = (nl < gate_d) ? nl : gate_d;          // monotone ratchet
        A = 0.5f * (me.w - gate_d) - 1.0e-4f;
    }
    u32* dst = (u32*)(part16 + (size_t)q * 256 + r * 16);
#pragma unroll
    for (int t = 0; t < 8; ++t) {
        u32 a = kk[2 * t], c = kk[2 * t + 1];
        u32 i0 = (a == 0xFFFFFFFFu) ? 0xFFFFu : (a & 0x1FFFu);
        u32 i1 = (c == 0xFFFFFFFFu) ? 0xFFFFu : (c & 0x1FFFu);
        dst[t] = i0 | (i1 << 16);
    }
}

// ---------------------------------------------------------------- KNN merge
// One WAVE per query. Keys are (hi=fordkey(exact d), lo=idx) pairs kept in
// separate u32 regs. Extraction rounds reduce ONLY the hi word (6 x {shfl_xor
// + v_min_u32}); the winner's lo is fetched with one shuffle when the hi-min
// is unique (ballot popcount == 1, the ~always case, wave-uniform branch) or
// via a second masked u32 reduce on a genuine distance tie. Selection order
// is exactly (d, idx)-lexicographic == the serial exact-key merge.
__global__ __launch_bounds__(256) void knn_merge(const float4* __restrict__ pts,
                                                 const unsigned short* __restrict__ part16,
                                                 int* __restrict__ idx16) {
    int wavein = threadIdx.x >> 6, lane = threadIdx.x & 63;
    int q = blockIdx.x * 4 + wavein;
    int b = q >> 13;
    float4 me = pts[q];
    ushort4 e = *(const ushort4*)(part16 + (size_t)q * 256 + lane * 4);
    u64 k0, k1, k2, k3;
    {
        u32 id, ida;
        id = e.x; ida = (id != 0xFFFFu) ? id : 0u;
        k0 = (id != 0xFFFFu) ? (((u64)fordkey(pdist(me, pts[b * NPTS + ida])) << 32) | id) : ~0ull;
        id = e.y; ida = (id != 0xFFFFu) ? id : 0u;
        k1 = (id != 0xFFFFu) ? (((u64)fordkey(pdist(me, pts[b * NPTS + ida])) << 32) | id) : ~0ull;
        id = e.z; ida = (id != 0xFFFFu) ? id : 0u;
        k2 = (id != 0xFFFFu) ? (((u64)fordkey(pdist(me, pts[b * NPTS + ida])) << 32) | id) : ~0ull;
        id = e.w; ida = (id != 0xFFFFu) ? id : 0u;
        k3 = (id != 0xFFFFu) ? (((u64)fordkey(pdist(me, pts[b * NPTS + ida])) << 32) | id) : ~0ull;
    }
    // sort4 (network: (0,1)(2,3)(0,2)(1,3)(1,2)) on full u64 keys (reg-only)
    u64 t;
    if (k1 < k0) { t = k0; k0 = k1; k1 = t; }
    if (k3 < k2) { t = k2; k2 = k3; k3 = t; }
    if (k2 < k0) { t = k0; k0 = k2; k2 = t; }
    if (k3 < k1) { t = k1; k1 = k3; k3 = t; }
    if (k2 < k1) { t = k1; k1 = k2; k2 = t; }

    u32 curh = (u32)(k0 >> 32), curl = (u32)k0;
    int head = 0;
    u32 gotl = 0;
#pragma unroll
    for (int it = 0; it < 16; ++it) {
        u32 mh = curh;
#pragma unroll
        for (int s = 32; s >= 1; s >>= 1) {
            u32 o = __shfl_xor(mh, s);
            mh = (o < mh) ? o : mh;
        }
        u64 bal = __ballot(curh == mh);
        u32 wlo;
        if (__builtin_popcountll(bal) == 1) {         // unique hi-min (~always)
            int wl = __builtin_ctzll(bal);
            wlo = __shfl(curl, wl);
        } else {                                      // exact-distance tie: min idx
            u32 cand = (curh == mh) ? curl : 0xFFFFFFFFu;
#pragma unroll
            for (int s = 32; s >= 1; s >>= 1) {
                u32 o = __shfl_xor(cand, s);
                cand = (o < cand) ? o : cand;
            }
            wlo = cand;
        }
        if (curh == mh && curl == wlo) {              // winner advances its head
            head++;
            u64 nx = (head == 1) ? k1 : (head == 2) ? k2 : (head == 3) ? k3 : ~0ull;
            curh = (u32)(nx >> 32);
            curl = (u32)nx;
        }
        if (lane == it) gotl = wlo;
    }
    if (lane < 16) idx16[q * KNN + lane] = (int)gotl;
}

// ---------------------------------------------------------------- GEMM 32-row
// X fp32, W pre-packed bf16 pairs (global, staged to LDS), accum fp32.
// MODE 0: Vf   = X @ Wv + bv                      -> fp32
// MODE 1: T1   = X @ Wp2 + bp2 + add(vagg)        -> fp32
// MODE 2: out  = featb + gamma*(X @ Wo + bo)      -> fp32
template <int MODE>
__global__ __launch_bounds__(256) void gemm32(const float* __restrict__ X,
                                              const u32* __restrict__ Wb,
                                              const float* __restrict__ bias,
                                              const float* __restrict__ add,
                                              const float* __restrict__ featb,
                                              const float* __restrict__ gammap,
                                              float* __restrict__ outv) {
    __shared__ u32 Ws[DIM * DIM / 2];   // 32 KB packed bf16 pairs, [c][d/2]
    __shared__ float Xs[8 * DIM];       // 4 KB
    __shared__ float bs[DIM];
    int tid = threadIdx.x;
    {
        const uint4* src = (const uint4*)Wb;
        uint4* dst = (uint4*)Ws;
        for (int i = tid; i < DIM * DIM / 8; i += 256) dst[i] = src[i];
    }
    if (tid < 128) bs[tid] = bias[tid];
    float gamma = 0.f;
    if (MODE == 2) gamma = *gammap;

    int rowBase = blockIdx.x * 32;
    int d4 = (tid & 31) * 4;
    int row = tid >> 5;  // 0..7

    for (int it = 0; it < 4; ++it) {
        int r0 = rowBase + it * 8;
        __syncthreads();
        ((float4*)Xs)[tid] = ((const float4*)(X + (size_t)r0 * DIM))[tid];
        __syncthreads();

        float a0 = bs[d4], a1 = bs[d4 + 1], a2 = bs[d4 + 2], a3 = bs[d4 + 3];
        const float* xr = &Xs[row * DIM];
#pragma unroll 8
        for (int c = 0; c < DIM; ++c) {
            float x = xr[c];
            uint2 w = *(const uint2*)&Ws[c * (DIM / 2) + (d4 >> 1)];
            a0 = fmaf(x, __uint_as_float(w.x << 16), a0);
            a1 = fmaf(x, __uint_as_float(w.x & 0xFFFF0000u), a1);
            a2 = fmaf(x, __uint_as_float(w.y << 16), a2);
            a3 = fmaf(x, __uint_as_float(w.y & 0xFFFF0000u), a3);
        }
        size_t off = (size_t)(r0 + row) * DIM + d4;
        if (MODE == 1) {
            float4 ad = *(const float4*)(add + off);
            a0 += ad.x; a1 += ad.y; a2 += ad.z; a3 += ad.w;
        }
        if (MODE == 2) {
            float4 fb = *(const float4*)(featb + off);
            a0 = fmaf(gamma, a0, fb.x);
            a1 = fmaf(gamma, a1, fb.y);
            a2 = fmaf(gamma, a2, fb.z);
            a3 = fmaf(gamma, a3, fb.w);
        }
        *(float4*)(outv + off) = make_float4(a0, a1, a2, a3);
    }
}

// ---------------------------------------------------------------- stage C
// One wave per point. h kept entirely in REGISTERS (h_lo/h_hi[16], constant-
// indexed via full unroll): no LDS -> no occupancy cap, no ds-ops in the
// serial per-k chain. Loop2 fully unrolled: all 32 coalesced Vf gathers
// depend only on myidx (known upfront) -> issued while softmax completes.
__global__ __launch_bounds__(256, 5) void stage_c(const float4* __restrict__ pts,
                                               const int* __restrict__ idx16,
                                               const float* __restrict__ sK,
                                               const float* __restrict__ w2,
                                               const float* __restrict__ Wp1,
                                               const float* __restrict__ bp1,
                                               const float* __restrict__ Vf,
                                               float* __restrict__ vagg,
                                               float* __restrict__ hbar) {
    int wavein = threadIdx.x >> 6;
    int lid = threadIdx.x & 63;
    int p = blockIdx.x * 4 + wavein;
    int b = p >> 13;
    float4 me = pts[p];

    float wx_lo = Wp1[lid],        wx_hi = Wp1[64 + lid];
    float wy_lo = Wp1[128 + lid],  wy_hi = Wp1[192 + lid];
    float wz_lo = Wp1[256 + lid],  wz_hi = Wp1[320 + lid];
    float bl    = bp1[lid],        bh    = bp1[64 + lid];
    float w2l   = w2[lid],         w2h   = w2[64 + lid];

    int myidx = idx16[p * KNN + (lid & 15)];
    float h_lo[KNN], h_hi[KNN];
    float sc = -INFINITY;

#pragma unroll
    for (int k = 0; k < KNN; ++k) {
        int j = __shfl(myidx, k);
        int g = b * NPTS + j;
        float4 nb = pts[g];
        float rx = me.x - nb.x, ry = me.y - nb.y, rz = me.z - nb.z;
        float hl = fmaxf(0.f, fmaf(rx, wx_lo, fmaf(ry, wy_lo, fmaf(rz, wz_lo, bl))));
        float hh = fmaxf(0.f, fmaf(rx, wx_hi, fmaf(ry, wy_hi, fmaf(rz, wz_hi, bh))));
        h_lo[k] = hl;
        h_hi[k] = hh;
        float s = fmaf(hl, w2l, hh * w2h);
#pragma unroll
        for (int m = 32; m >= 1; m >>= 1) s += __shfl_xor(s, m);
        float score = s - sK[g];
        if (lid == k) sc = score;
    }
    float mx = sc;
#pragma unroll
    for (int m = 8; m >= 1; m >>= 1) mx = fmaxf(mx, __shfl_xor(mx, m));
    float e = (lid < 16) ? __expf(sc - mx) : 0.f;
    float ssum = e;
#pragma unroll
    for (int m = 8; m >= 1; m >>= 1) ssum += __shfl_xor(ssum, m);
    float a = e / ssum;

    float acc_lo = 0.f, acc_hi = 0.f, hb_lo = 0.f, hb_hi = 0.f;
#pragma unroll
    for (int k = 0; k < KNN; ++k) {
        float ak = __shfl(a, k);
        int j = __shfl(myidx, k);
        size_t g = (size_t)(b * NPTS + j) * DIM;
        acc_lo = fmaf(ak, Vf[g + lid], acc_lo);
        acc_hi = fmaf(ak, Vf[g + 64 + lid], acc_hi);
        hb_lo = fmaf(ak, h_lo[k], hb_lo);
        hb_hi = fmaf(ak, h_hi[k], hb_hi);
    }
    size_t o = (size_t)p * DIM;
    vagg[o + lid] = acc_lo;
    vagg[o + 64 + lid] = acc_hi;
    hbar[o + lid] = hb_lo;
    hbar[o + 64 + lid] = hb_hi;
}

// ---------------------------------------------------------------- launcher
extern "C" void kernel_launch(void* const* d_in, const int* in_sizes, int n_in,
                              void* d_out, int out_size, void* d_ws, size_t ws_size,
                              hipStream_t stream) {
    const float* xyz   = (const float*)d_in[0];
    const float* feat  = (const float*)d_in[1];
    // d_in[2]=Wq, d_in[3]=bq, d_in[5]=bk: provably irrelevant (softmax shift-invariance)
    const float* Wk    = (const float*)d_in[4];
    const float* Wv    = (const float*)d_in[6];
    const float* bv    = (const float*)d_in[7];
    const float* Wp1   = (const float*)d_in[8];
    const float* bp1   = (const float*)d_in[9];
    const float* Wp2   = (const float*)d_in[10];
    const float* bp2   = (const float*)d_in[11];
    const float* Wo    = (const float*)d_in[12];
    const float* bo    = (const float*)d_in[13];
    const float* gamma = (const float*)d_in[14];
    float* out = (float*)d_out;

    char* ws = (char*)d_ws;
    const size_t KB = 1024, MB = 1024 * 1024;
    float*  wk    = (float*)(ws + 0);                // 512 B
    float*  w2    = (float*)(ws + 4 * KB);           // 512 B
    float4* pts   = (float4*)(ws + 16 * KB);         // 512 KB
    float*  sKv   = (float*)(ws + 544 * KB);         // 128 KB
    u32*    Wb    = (u32*)(ws + 688 * KB);           // 96 KB (Wv|Wp2|Wo bf16)
    float*  Tq    = (float*)(ws + 1 * MB);           // 128 KB (16th-of-kept bound)
    // dl16q (8 MB) aliases the part16 region: dead before partial writes part16.
    float*  dl16q = (float*)(ws + 5 * MB);           // 8 MB (NROWS x 64 window dists)
    unsigned short* part16 = (unsigned short*)(ws + 5 * MB); // 16 MB, query-major, dead after merge
    float*  vagg  = (float*)(ws + 5 * MB);           // 16 MB, aliases dead part16
    float*  hbarp = (float*)(ws + 21 * MB);          // 16 MB
    int*    idx16 = (int*)(ws + 37 * MB);            // 2 MB
    float*  Vf    = (float*)(ws + 39 * MB);          // 16 MB, dead after stage_c
    float*  T1    = (float*)(ws + 39 * MB);          // aliases Vf  (total 55 MB)

    prep_weights<<<1, 256, 0, stream>>>(Wk, Wp2, wk, w2);
    conv_weights<<<96, 256, 0, stream>>>(Wv, Wp2, Wo, Wb);
    prep_points<<<NROWS / 4, 256, 0, stream>>>(xyz, feat, wk, pts, sKv);
    gemm32<0><<<1024, 256, 0, stream>>>(feat, Wb, bv, nullptr, nullptr, nullptr, Vf);
    knn_limpass<<<dim3(NROWS / 256, NWIN), 256, 0, stream>>>(pts, dl16q);
    bound_merge<<<NROWS / 4, 256, 0, stream>>>(dl16q, Tq);
    knn_partial<<<dim3(NROWS / 256, SPLITS), 256, 0, stream>>>(pts, Tq, part16);
    knn_merge<<<NROWS / 4, 256, 0, stream>>>(pts, part16, idx16);
    stage_c<<<NROWS / 4, 256, 0, stream>>>(pts, idx16, sKv, w2, Wp1, bp1, Vf, vagg, hbarp);
    gemm32<1><<<1024, 256, 0, stream>>>(hbarp, Wb + 8192, bp2, vagg, nullptr, nullptr, T1);
    gemm32<2><<<1024, 256, 0, stream>>>(T1, Wb + 16384, bo, nullptr, feat, gamma, out);
}